// Round 8
// baseline (28016.385 us; speedup 1.0000x reference)
//
#include <hip/hip_runtime.h>
#include <stdint.h>

// ODE-LSTM (PersonActivityModel): B=256,T=128,IN=64,H=512,C=11, fp32 in/out.
//
// u-space RK4 folding: M = W2^T W1^T, d = b2·W1^T:
//   u1 = h·W1^T+b1; D_i = tanh(u_i)·M; u2=u1+.5dt(D1+d); u3=u1+.5dt(D2+d);
//   u4=u1+dt(D3+d); SM=D1+2D2+2D3+D4; u_next=u1+(dt/6)SM+dt·d;
//   S=t1+2t2+2t3+t4 over 3 unfolds; h += (dt/6)(S_tot·W2^T)+3dt·b2.
// out = h·(Wc·Wo)^T + (Wc·bo + bc) deferred; gates z = [h|x]·[Whh|Wih]^T.
//
// ROUND-13: ONE CU PER CLUSTER — no cross-WG sync at all. Rounds 8-12 proved
// the per-phase cross-CU slot (~2.3us of serialized LLC RTTs) is a floor:
// 1792 phases x 2.3us = 4.1ms for ANY cross-CU-per-phase design. This kernel
// keeps each cluster's entire 14-phase chain on one CU: 16 WGs x 512 threads
// (8 waves, 2/SIMD). M (512KB) split per wave (64 cols = 4 slabs of 512x16):
// 2 slabs in VGPR (mreg, 128 VGPRs), 1 slab in LDS (128 KB total), 1 slab
// streamed from L2 each M-phase. ACT (16x520 fp16) in LDS. Phase sync =
// __syncthreads (~100ns) instead of 2.3us. Gates/W1/W2 B-frags stream from
// L2 (weights ~6MB, L2-resident; 2 WGs/XCD). State (c,h,u1,SS,SM) fp32 in
// VGPRs — identical arithmetic to round 9. Zero atomics/flags/polls: no
// hang modes, no replay staleness, no memsets.

#define H_  512
#define B_  256
#define T_  128
#define IN_ 64
#define NC_ 11
#define LD_ 520   // padded LDS row stride (halfs)

typedef _Float16 h8v __attribute__((ext_vector_type(8)));
typedef float    f4v __attribute__((ext_vector_type(4)));
typedef unsigned long long ull;

__device__ __forceinline__ float fsigm(float x) { return 1.0f / (1.0f + __expf(-x)); }
__device__ __forceinline__ float ftanh(float x) { return 1.0f - 2.0f / (1.0f + __expf(2.0f * x)); }

// ---------------- prep kernels (fp32 weights -> fp16 MFMA B-fragment tables) ----------------

__global__ void prep_M(const float* __restrict__ W1, const float* __restrict__ W2,
                       float* __restrict__ Mtmp) {
  __shared__ float w1s[8][512];
  int tid = threadIdx.x;
  int n0 = blockIdx.x * 8;
  for (int i = tid; i < 8 * 512; i += 256) {
    int nn = i >> 9, m = i & 511;
    w1s[nn][m] = W1[(n0 + nn) * 512 + m];
  }
  __syncthreads();
  float acc0[8] = {0,0,0,0,0,0,0,0}, acc1[8] = {0,0,0,0,0,0,0,0};
  for (int m = 0; m < 512; ++m) {
    float a = W2[m * 512 + tid];
    float b = W2[m * 512 + 256 + tid];
#pragma unroll
    for (int j = 0; j < 8; ++j) { acc0[j] += a * w1s[j][m]; acc1[j] += b * w1s[j][m]; }
  }
  for (int j = 0; j < 8; ++j) {
    Mtmp[(size_t)tid * 512 + n0 + j]         = acc0[j];
    Mtmp[(size_t)(tid + 256) * 512 + n0 + j] = acc1[j];
  }
}

__global__ void prep_small(const float* __restrict__ W1, const float* __restrict__ b2,
                           const float* __restrict__ Wc, const float* __restrict__ Wo,
                           const float* __restrict__ bo, const float* __restrict__ bc,
                           const float* __restrict__ bih, const float* __restrict__ bhh,
                           float* __restrict__ dvec, float* __restrict__ Wco,
                           float* __restrict__ bprime, float* __restrict__ zbs) {
  __shared__ float wcs[NC_ * 512];
  int tid = threadIdx.x;
  if (blockIdx.x == 0) {
    for (int n = tid; n < 512; n += 256) {
      float acc = 0.f;
      for (int m = 0; m < 512; ++m) acc += b2[m] * W1[n * 512 + m];
      dvec[n] = acc;
    }
  } else if (blockIdx.x == 1) {
    if (tid < NC_) {
      float acc = bc[tid];
      for (int m = 0; m < 512; ++m) acc += Wc[tid * 512 + m] * bo[m];
      bprime[tid] = acc;
    }
    for (int i = tid; i < 2048; i += 256) zbs[i] = bih[i] + bhh[i];
  } else {
    for (int i = tid; i < NC_ * 512; i += 256) wcs[i] = Wc[i];
    __syncthreads();
    int h = (blockIdx.x - 2) * 256 + tid;
    float acc[NC_];
#pragma unroll
    for (int c = 0; c < NC_; ++c) acc[c] = 0.f;
    for (int m = 0; m < 512; ++m) {
      float wo = Wo[m * 512 + h];
#pragma unroll
      for (int c = 0; c < NC_; ++c) acc[c] += wo * wcs[c * 512 + m];
    }
    for (int c = 0; c < NC_; ++c) Wco[c * 512 + h] = acc[c];
  }
}

// B-frag tables: frag fb = 64 lanes x 8 halfs (1KB). B[k][n]:
// lane holds n = tile*16+(lane&15), k = kc*32+((lane>>4)&3)*8+j.
__global__ void prep_wtilde(const float* __restrict__ Whh, const float* __restrict__ Wih,
                            _Float16* __restrict__ Wtil) {
  int gidx = blockIdx.x * 256 + threadIdx.x;  // 2304 fb * 64 lanes
  int lane = gidx & 63, fb = gidx >> 6;
  int kc = fb % 18; int t2 = fb / 18;
  int t = t2 & 31, g = t2 >> 5;
  int n = g * 512 + t * 16 + (lane & 15);
  int k = kc * 32 + ((lane >> 4) & 3) * 8;
  _Float16 vals[8];
  if (k < 512) {
#pragma unroll
    for (int j = 0; j < 8; ++j) vals[j] = (_Float16)Whh[(size_t)n * 512 + k + j];
  } else {
#pragma unroll
    for (int j = 0; j < 8; ++j) vals[j] = (_Float16)Wih[(size_t)n * 64 + (k - 512) + j];
  }
  *(h8v*)(Wtil + (size_t)fb * 512 + lane * 8) = *(h8v*)vals;
}

__global__ void prep_fragW(const float* __restrict__ W, _Float16* __restrict__ dst) {
  int gidx = blockIdx.x * 256 + threadIdx.x;  // 512 fb * 64 lanes
  int lane = gidx & 63, fb = gidx >> 6;
  int t = fb >> 4, kc = fb & 15;
  int n = t * 16 + (lane & 15);
  int k = kc * 32 + ((lane >> 4) & 3) * 8;
  _Float16 vals[8];
#pragma unroll
  for (int j = 0; j < 8; ++j) vals[j] = (_Float16)W[(size_t)n * 512 + k + j];
  *(h8v*)(dst + (size_t)fb * 512 + lane * 8) = *(h8v*)vals;
}

__global__ void prep_fragM(const float* __restrict__ Mtmp, _Float16* __restrict__ dst) {
  int gidx = blockIdx.x * 256 + threadIdx.x;
  int lane = gidx & 63, fb = gidx >> 6;
  int t = fb >> 4, kc = fb & 15;
  int n = t * 16 + (lane & 15);
  int k = kc * 32 + ((lane >> 4) & 3) * 8;
  _Float16 vals[8];
#pragma unroll
  for (int j = 0; j < 8; ++j) vals[j] = (_Float16)Mtmp[(size_t)(k + j) * 512 + n];
  *(h8v*)(dst + (size_t)fb * 512 + lane * 8) = *(h8v*)vals;
}

// ---------------- recurrence: one cluster (16 rows) per CU ----------------

// Write-back of a phase's 16 outputs per thread into ACT, double-barriered:
// barrier 1 = all waves done READING ACT (WAR); barrier 2 = staged (RAW).
#define STORE_HOLD(hold) do {                                                  \
    __syncthreads();                                                           \
    _Pragma("unroll") for (int j = 0; j < 4; ++j)                              \
      _Pragma("unroll") for (int r = 0; r < 4; ++r)                            \
        ACT[(quad * 4 + r) * LD_ + w * 64 + j * 16 + lm] = (_Float16)hold[j][r]; \
    __syncthreads();                                                           \
  } while (0)

// M-phase matmul: D(16x64 per wave) = A(16x512 from ACT) @ M-slabs.
// j=0,1 from VGPR mreg; j=2 from LDS Mlds[w]; j=3 streamed from L2 (MF).
#define MM_M(a0, a1, a2, a3) do {                                              \
    const _Float16* arow = ACT + lm * LD_ + quad * 8;                          \
    _Pragma("unroll") for (int kc = 0; kc < 16; ++kc) {                        \
      h8v av = *(const h8v*)(arow + kc * 32);                                  \
      a0 = __builtin_amdgcn_mfma_f32_16x16x32_f16(av, mreg[kc], a0, 0, 0, 0);  \
      a1 = __builtin_amdgcn_mfma_f32_16x16x32_f16(av, mreg[16 + kc], a1, 0, 0, 0); \
      a2 = __builtin_amdgcn_mfma_f32_16x16x32_f16(av, Mlds[w][kc][lane], a2, 0, 0, 0); \
      a3 = __builtin_amdgcn_mfma_f32_16x16x32_f16(av, mf3[(size_t)kc * 64], a3, 0, 0, 0); \
    }                                                                          \
  } while (0)

// W-phase matmul: B-frags (4 tiles) streamed from L2 table wf (base incl lane).
#define MM_W(wf, a0, a1, a2, a3) do {                                          \
    const _Float16* arow = ACT + lm * LD_ + quad * 8;                          \
    _Pragma("unroll") for (int kc = 0; kc < 16; ++kc) {                        \
      h8v av = *(const h8v*)(arow + kc * 32);                                  \
      a0 = __builtin_amdgcn_mfma_f32_16x16x32_f16(av, wf[(size_t)(0 * 16 + kc) * 64], a0, 0, 0, 0); \
      a1 = __builtin_amdgcn_mfma_f32_16x16x32_f16(av, wf[(size_t)(1 * 16 + kc) * 64], a1, 0, 0, 0); \
      a2 = __builtin_amdgcn_mfma_f32_16x16x32_f16(av, wf[(size_t)(2 * 16 + kc) * 64], a2, 0, 0, 0); \
      a3 = __builtin_amdgcn_mfma_f32_16x16x32_f16(av, wf[(size_t)(3 * 16 + kc) * 64], a3, 0, 0, 0); \
    }                                                                          \
  } while (0)

__launch_bounds__(512, 2)
__global__ void recur(const float* __restrict__ x,
                      const float* __restrict__ tin,
                      const float* __restrict__ zbs,
                      const float* __restrict__ b1g,
                      const float* __restrict__ b2g,
                      const float* __restrict__ dvec,
                      const _Float16* __restrict__ Wtil,
                      const _Float16* __restrict__ W1T,
                      const _Float16* __restrict__ W2T,
                      const _Float16* __restrict__ MF,
                      _Float16* __restrict__ Hsave) {
  const int c = blockIdx.x;                       // cluster = 16 batch rows
  const int tid = threadIdx.x, w = tid >> 6, lane = tid & 63;
  const int lm = lane & 15, quad = lane >> 4;

  __shared__ __align__(16) h8v Mlds[8][16][64];   // 128 KB: per-wave M slab (t=4w+2)
  __shared__ __align__(16) _Float16 ACT[16 * LD_];// 16.25 KB

  h8v mreg[32];                                   // M slabs t=4w+0, 4w+1 (128 VGPRs)
  {
    const h8v* mf = (const h8v*)MF;
#pragma unroll
    for (int kc = 0; kc < 16; ++kc) {
      mreg[kc]          = mf[((size_t)((4 * w + 0) * 16 + kc)) * 64 + lane];
      mreg[16 + kc]     = mf[((size_t)((4 * w + 1) * 16 + kc)) * 64 + lane];
      Mlds[w][kc][lane] = mf[((size_t)((4 * w + 2) * 16 + kc)) * 64 + lane];
    }
  }
  for (int i = tid; i < 16 * LD_; i += 512) ACT[i] = (_Float16)0.f;

  const h8v* mf3 = (const h8v*)MF + ((size_t)((4 * w + 3) * 16)) * 64 + lane;
  const h8v* w1f = (const h8v*)W1T + ((size_t)((4 * w) * 16)) * 64 + lane;
  const h8v* w2f = (const h8v*)W2T + ((size_t)((4 * w) * 16)) * 64 + lane;
  const h8v* wtf = (const h8v*)Wtil + ((size_t)((4 * w) * 18)) * 64 + lane;

  float c_[4][4] = {}, h_[4][4] = {};
  float u1a[4][4], SSa[4][4], SMa[4][4];
  __syncthreads();

#pragma unroll 1
  for (int ts = 0; ts < T_; ++ts) {
    float dt_[4];
#pragma unroll
    for (int r = 0; r < 4; ++r)
      dt_[r] = tin[(c * 16 + quad * 4 + r) * T_ + ts] * (1.0f / 3.0f);

    // ---- P1: gates z = [h|x]·Wtil^T (K=576; B streamed from L2) ----
    {
      f4v hold[4];
#pragma unroll
      for (int j = 0; j < 4; ++j) {
        f4v z0 = {0,0,0,0}, z1 = {0,0,0,0}, z2 = {0,0,0,0}, z3 = {0,0,0,0};
        const h8v* bj = wtf + (size_t)j * 18 * 64;
        const _Float16* arow = ACT + lm * LD_ + quad * 8;
#pragma unroll
        for (int kc = 0; kc < 16; ++kc) {
          h8v av = *(const h8v*)(arow + kc * 32);
          z0 = __builtin_amdgcn_mfma_f32_16x16x32_f16(av, bj[((size_t)0 * 32 * 18 + kc) * 64], z0, 0, 0, 0);
          z1 = __builtin_amdgcn_mfma_f32_16x16x32_f16(av, bj[((size_t)1 * 32 * 18 + kc) * 64], z1, 0, 0, 0);
          z2 = __builtin_amdgcn_mfma_f32_16x16x32_f16(av, bj[((size_t)2 * 32 * 18 + kc) * 64], z2, 0, 0, 0);
          z3 = __builtin_amdgcn_mfma_f32_16x16x32_f16(av, bj[((size_t)3 * 32 * 18 + kc) * 64], z3, 0, 0, 0);
        }
        const float* xr = x + ((size_t)(c * 16 + lm) * T_ + ts) * IN_ + quad * 8;
#pragma unroll
        for (int kx = 0; kx < 2; ++kx) {
          float4 f0 = *(const float4*)(xr + kx * 32);
          float4 f1 = *(const float4*)(xr + kx * 32 + 4);
          h8v av;
          av[0] = (_Float16)f0.x; av[1] = (_Float16)f0.y; av[2] = (_Float16)f0.z; av[3] = (_Float16)f0.w;
          av[4] = (_Float16)f1.x; av[5] = (_Float16)f1.y; av[6] = (_Float16)f1.z; av[7] = (_Float16)f1.w;
          int kc = 16 + kx;
          z0 = __builtin_amdgcn_mfma_f32_16x16x32_f16(av, bj[((size_t)0 * 32 * 18 + kc) * 64], z0, 0, 0, 0);
          z1 = __builtin_amdgcn_mfma_f32_16x16x32_f16(av, bj[((size_t)1 * 32 * 18 + kc) * 64], z1, 0, 0, 0);
          z2 = __builtin_amdgcn_mfma_f32_16x16x32_f16(av, bj[((size_t)2 * 32 * 18 + kc) * 64], z2, 0, 0, 0);
          z3 = __builtin_amdgcn_mfma_f32_16x16x32_f16(av, bj[((size_t)3 * 32 * 18 + kc) * 64], z3, 0, 0, 0);
        }
        const int colj = w * 64 + j * 16 + lm;
#pragma unroll
        for (int r = 0; r < 4; ++r) {
          float zi = z0[r] + zbs[colj], zf = z1[r] + zbs[512 + colj];
          float zg = z2[r] + zbs[1024 + colj], zo = z3[r] + zbs[1536 + colj];
          float cv = fsigm(zf) * c_[j][r] + fsigm(zi) * ftanh(zg);
          c_[j][r] = cv;
          float hv = fsigm(zo) * ftanh(cv);
          h_[j][r] = hv;
          hold[j][r] = hv;
        }
      }
      STORE_HOLD(hold);
    }

    // ---- P2: u1 = h·W1^T + b1 ----
    {
      f4v a0 = {0,0,0,0}, a1 = {0,0,0,0}, a2 = {0,0,0,0}, a3 = {0,0,0,0};
      MM_W(w1f, a0, a1, a2, a3);
      f4v D[4] = {a0, a1, a2, a3};
      f4v hold[4];
#pragma unroll
      for (int j = 0; j < 4; ++j) {
        float b1j = b1g[w * 64 + j * 16 + lm];
#pragma unroll
        for (int r = 0; r < 4; ++r) {
          float uv = D[j][r] + b1j;
          u1a[j][r] = uv;
          float t1v = ftanh(uv);
          SSa[j][r] = t1v;
          hold[j][r] = t1v;
        }
      }
      STORE_HOLD(hold);
    }

    // ---- 3 RK4 unfolds in u-space ----
#pragma unroll 1
    for (int uf = 0; uf < 3; ++uf) {
      {  // t2
        f4v a0 = {0,0,0,0}, a1 = {0,0,0,0}, a2 = {0,0,0,0}, a3 = {0,0,0,0};
        MM_M(a0, a1, a2, a3);
        f4v D[4] = {a0, a1, a2, a3};
        f4v hold[4];
#pragma unroll
        for (int j = 0; j < 4; ++j) {
          float dvj = dvec[w * 64 + j * 16 + lm];
#pragma unroll
          for (int r = 0; r < 4; ++r) {
            float Dv = D[j][r];
            float u2 = u1a[j][r] + 0.5f * dt_[r] * (Dv + dvj);
            SMa[j][r] = Dv;
            float t2v = ftanh(u2);
            SSa[j][r] += 2.0f * t2v;
            hold[j][r] = t2v;
          }
        }
        STORE_HOLD(hold);
      }
      {  // t3
        f4v a0 = {0,0,0,0}, a1 = {0,0,0,0}, a2 = {0,0,0,0}, a3 = {0,0,0,0};
        MM_M(a0, a1, a2, a3);
        f4v D[4] = {a0, a1, a2, a3};
        f4v hold[4];
#pragma unroll
        for (int j = 0; j < 4; ++j) {
          float dvj = dvec[w * 64 + j * 16 + lm];
#pragma unroll
          for (int r = 0; r < 4; ++r) {
            float Dv = D[j][r];
            float u3 = u1a[j][r] + 0.5f * dt_[r] * (Dv + dvj);
            SMa[j][r] += 2.0f * Dv;
            float t3v = ftanh(u3);
            SSa[j][r] += 2.0f * t3v;
            hold[j][r] = t3v;
          }
        }
        STORE_HOLD(hold);
      }
      {  // t4 (publishes SSa at uf==2)
        f4v a0 = {0,0,0,0}, a1 = {0,0,0,0}, a2 = {0,0,0,0}, a3 = {0,0,0,0};
        MM_M(a0, a1, a2, a3);
        f4v D[4] = {a0, a1, a2, a3};
        f4v hold[4];
#pragma unroll
        for (int j = 0; j < 4; ++j) {
          float dvj = dvec[w * 64 + j * 16 + lm];
#pragma unroll
          for (int r = 0; r < 4; ++r) {
            float Dv = D[j][r];
            float u4 = u1a[j][r] + dt_[r] * (Dv + dvj);
            SMa[j][r] += 2.0f * Dv;
            float t4v = ftanh(u4);
            SSa[j][r] += t4v;
            hold[j][r] = (uf < 2) ? t4v : SSa[j][r];
          }
        }
        STORE_HOLD(hold);
      }
      if (uf < 2) {  // u_next
        f4v a0 = {0,0,0,0}, a1 = {0,0,0,0}, a2 = {0,0,0,0}, a3 = {0,0,0,0};
        MM_M(a0, a1, a2, a3);
        f4v D[4] = {a0, a1, a2, a3};
        f4v hold[4];
#pragma unroll
        for (int j = 0; j < 4; ++j) {
          float dvj = dvec[w * 64 + j * 16 + lm];
#pragma unroll
          for (int r = 0; r < 4; ++r) {
            float Dv = D[j][r];
            SMa[j][r] += Dv;
            float un = u1a[j][r] + (dt_[r] * (1.0f / 6.0f)) * SMa[j][r] + dt_[r] * dvj;
            u1a[j][r] = un;
            float t1v = ftanh(un);
            SSa[j][r] += t1v;
            hold[j][r] = t1v;
          }
        }
        STORE_HOLD(hold);
      }
    }

    // ---- P_h: h += (dt/6)·(S_tot·W2^T) + 3dt·b2 ; Hsave + publish h ----
    {
      f4v a0 = {0,0,0,0}, a1 = {0,0,0,0}, a2 = {0,0,0,0}, a3 = {0,0,0,0};
      MM_W(w2f, a0, a1, a2, a3);
      f4v D[4] = {a0, a1, a2, a3};
      f4v hold[4];
#pragma unroll
      for (int j = 0; j < 4; ++j) {
        const int colj = w * 64 + j * 16 + lm;
        float b2j = b2g[colj];
#pragma unroll
        for (int r = 0; r < 4; ++r) {
          float hv = h_[j][r] + (dt_[r] * (1.0f / 6.0f)) * D[j][r] + (3.0f * dt_[r]) * b2j;
          h_[j][r] = hv;
          hold[j][r] = hv;
          Hsave[((size_t)(ts + 1) * B_ + c * 16 + quad * 4 + r) * H_ + colj] = (_Float16)hv;
        }
      }
      STORE_HOLD(hold);
    }
  }
}

// ---------------- final projection: out = h·Wco^T + bprime ----------------
__global__ void final_out(const _Float16* __restrict__ Hsave,
                          const float* __restrict__ Wco,
                          const float* __restrict__ bprime,
                          float* __restrict__ out) {
  __shared__ float wcs[NC_][520];
  int tid = threadIdx.x;
  for (int i = tid; i < NC_ * 512; i += 256) wcs[i >> 9][i & 511] = Wco[i];
  __syncthreads();
  int r0 = blockIdx.x * 64;
  int rl = tid >> 4, cc = tid & 15;
  for (int pass = 0; pass < 4; ++pass) {
    int row = r0 + pass * 16 + rl;        // row = b*T + t
    int b = row >> 7, t = row & 127;
    const _Float16* hrow = Hsave + ((size_t)(t + 1) * B_ + b) * H_;
    if (cc < NC_) {
      float acc = 0.f;
      for (int k8 = 0; k8 < 64; ++k8) {
        h8v hv = *(const h8v*)(hrow + k8 * 8);
#pragma unroll
        for (int j = 0; j < 8; ++j) acc += (float)hv[j] * wcs[cc][k8 * 8 + j];
      }
      out[(size_t)row * NC_ + cc] = acc + bprime[cc];
    }
  }
}

extern "C" void kernel_launch(void* const* d_in, const int* in_sizes, int n_in,
                              void* d_out, int out_size, void* d_ws, size_t ws_size,
                              hipStream_t stream) {
  (void)in_sizes; (void)n_in; (void)out_size; (void)ws_size;
  const float* x   = (const float*)d_in[0];
  const float* tin = (const float*)d_in[1];
  const float* Wih = (const float*)d_in[2];
  const float* Whh = (const float*)d_in[3];
  const float* bih = (const float*)d_in[4];
  const float* bhh = (const float*)d_in[5];
  const float* W1  = (const float*)d_in[6];
  const float* b1  = (const float*)d_in[7];
  const float* W2  = (const float*)d_in[8];
  const float* b2  = (const float*)d_in[9];
  const float* Wo  = (const float*)d_in[10];
  const float* bo  = (const float*)d_in[11];
  const float* Wc  = (const float*)d_in[12];
  const float* bc  = (const float*)d_in[13];

  char* ws = (char*)d_ws;
  size_t off = 0;
  auto alloc = [&](size_t bytes) -> void* {
    void* p = ws + off;
    off = (off + bytes + 1023) & ~(size_t)1023;
    return p;
  };
  _Float16* Wtil  = (_Float16*)alloc((size_t)2304 * 512 * 2);
  _Float16* W1T   = (_Float16*)alloc((size_t)512 * 512 * 2);
  _Float16* W2T   = (_Float16*)alloc((size_t)512 * 512 * 2);
  _Float16* MF    = (_Float16*)alloc((size_t)512 * 512 * 2);
  float*    Mtmp  = (float*)alloc((size_t)512 * 512 * 4);
  float*    dvec  = (float*)alloc(512 * 4);
  float*    WcoF  = (float*)alloc((size_t)NC_ * 512 * 4);
  float*    bprim = (float*)alloc(64);
  float*    zbs   = (float*)alloc(2048 * 4);
  _Float16* Hsave = (_Float16*)alloc((size_t)(T_ + 1) * B_ * H_ * 2);

  prep_M<<<64, 256, 0, stream>>>(W1, W2, Mtmp);
  prep_small<<<4, 256, 0, stream>>>(W1, b2, Wc, Wo, bo, bc, bih, bhh,
                                    dvec, WcoF, bprim, zbs);
  prep_wtilde<<<576, 256, 0, stream>>>(Whh, Wih, Wtil);
  prep_fragW<<<128, 256, 0, stream>>>(W1, W1T);
  prep_fragW<<<128, 256, 0, stream>>>(W2, W2T);
  prep_fragM<<<128, 256, 0, stream>>>(Mtmp, MF);
  recur<<<16, 512, 0, stream>>>(x, tin, zbs, b1, b2, dvec,
                                Wtil, W1T, W2T, MF, Hsave);
  final_out<<<512, 256, 0, stream>>>(Hsave, WcoF, bprim, (float*)d_out);
}